// Round 10
// baseline (414.874 us; speedup 1.0000x reference)
//
#include <hip/hip_runtime.h>
#include <hip/hip_bf16.h>

#define T_LEN 256
#define B_DIM 128
#define EMB 1024
#define HID 1024
#define NLAB 50
#define M_ROWS (T_LEN * B_DIM)   // 32768
#define N3H 3072
#define KT 16                    // 1024 / BK=64

typedef __attribute__((ext_vector_type(8))) short short8;
typedef __attribute__((ext_vector_type(4))) float f32x4;

// ---- helpers ----
static __device__ __forceinline__ ushort f2b(float x) {
    unsigned u = __builtin_bit_cast(unsigned, x);
    unsigned lsb = (u >> 16) & 1u;
    u += 0x7fffu + lsb;
    return (ushort)(u >> 16);
}
static __device__ __forceinline__ float b2f(ushort u) {
    unsigned v = ((unsigned)u) << 16;
    return __builtin_bit_cast(float, v);
}
static __device__ __forceinline__ void gload16(const ushort* g, ushort* l) {
    __builtin_amdgcn_global_load_lds(
        (const __attribute__((address_space(1))) unsigned int*)g,
        (__attribute__((address_space(3))) unsigned int*)l,
        16, 0, 0);
}
static __device__ __forceinline__ float fast_sigmoid(float y) {
    return 1.f / (1.f + __expf(-y));
}
static __device__ __forceinline__ float fast_tanh(float y) {
    float e = __expf(2.f * y);
    return (e - 1.f) / (e + 1.f);
}

// ---- kernel 1: gather+convert AND W-transpose, fused into one launch ----
// Blocks 0..2047: x = bf16(emb[sentence]) (16 rows each).
// Blocks 2048..5119: Wt[n][k] = bf16(W[k][n]) (32x32 tile each).
__global__ __launch_bounds__(256) void prep(
    const int* __restrict__ sent, const float* __restrict__ emb,
    const float* __restrict__ W,
    ushort* __restrict__ xb, ushort* __restrict__ Wt)
{
    __shared__ float tile[32][33];
    const int wg = blockIdx.x;
    if (wg < 2048) {
        const int row = wg * 16 + (threadIdx.x >> 4);
        const int seg = threadIdx.x & 15;
        const size_t src = (size_t)sent[row] * EMB;
        const float4* ep = (const float4*)(emb + src);
        ushort4* op = (ushort4*)(xb + (size_t)row * EMB);
#pragma unroll
        for (int j = 0; j < 16; j++) {
            float4 v = ep[seg + j * 16];
            ushort4 o;
            o.x = f2b(v.x); o.y = f2b(v.y); o.z = f2b(v.z); o.w = f2b(v.w);
            op[seg + j * 16] = o;
        }
    } else {
        const int bx = wg - 2048;               // 96 n-tiles x 32 k-tiles
        const int n0 = (bx % 96) * 32, k0 = (bx / 96) * 32;
        const int tx = threadIdx.x & 31, ty = threadIdx.x >> 5;   // 32 x 8
#pragma unroll
        for (int j = 0; j < 32; j += 8)
            tile[ty + j][tx] = W[(size_t)(k0 + ty + j) * N3H + n0 + tx];
        __syncthreads();
#pragma unroll
        for (int j = 0; j < 32; j += 8)
            Wt[(size_t)(n0 + ty + j) * EMB + k0 + tx] = f2b(tile[tx][ty + j]);
    }
}

// ---- kernel 2: 256x256, BK=64, 8 waves, 4-phase interleaved pipeline ----
// Layout (proven R6/R8: coalesced staging, 0 read conflicts):
// row-major [256][64] bf16 tiles; granule g of row r at slot g^(r&7);
// linear gload_lds dest; source granule pre-permuted within the row's 128B;
// read offset (octet)^(l15&7), mi/ni-independent.
// Schedule (m201-style): per K-tile 4 phases {ds_reads; stage; barrier;
// lgkmcnt(0); setprio(1) 16 MFMA setprio(0); barrier}; stage front-loaded
// in phases 0-1; one vmcnt(0) at tile end (depth-1 double buffer).
__global__ __launch_bounds__(512) void gemm256(
    const ushort* __restrict__ A, const ushort* __restrict__ Bt,
    const float* __restrict__ bias,
    ushort* __restrict__ zb, ushort* __restrict__ fb, ushort* __restrict__ ob)
{
    __shared__ ushort LDS[65536];   // 2 bufs x (A 32KB + B 32KB) = 128 KB

    const int tid = threadIdx.x;
    const int lane = tid & 63;
    const int w = tid >> 6;
    const int wr = w >> 2, wc = w & 3;          // 2x4 waves, wave-tile 128x64
    const int l15 = lane & 15, lh = lane >> 4;

    const int wg = blockIdx.x;
    const ushort *Ab, *Bb;
    const float* bptr;
    ushort* dst;
    int rowbase, colbase, Mvalid, maxrow;
    bool use_tanh;
    if (wg < 1024) {
        const int w2 = (wg & 7) * 128 + (wg >> 3);   // XCD-chunked, nt-fastest
        const int mt = w2 >> 3, nt = w2 & 7;
        Ab = A + (size_t)mt * 256 * EMB;
        Bb = Bt + (size_t)nt * 256 * EMB;
        bptr = bias + nt * 256;
        rowbase = mt * 256; Mvalid = 256; maxrow = 255;
        if (nt < 4) { dst = zb; colbase = nt * 256; use_tanh = true; }
        else        { dst = fb; colbase = nt * 256 - 1024; use_tanh = false; }
    } else {
        const int q = wg - 1024;
        Ab = A + (size_t)(M_ROWS - 128) * EMB;
        Bb = Bt + (size_t)(2048 + q * 256) * EMB;
        bptr = bias + 2048 + q * 256;
        rowbase = 0; colbase = q * 256; Mvalid = 128; maxrow = 127;
        dst = ob; use_tanh = false;
    }

    // stage-side: 4 A-chunks + 4 B-chunks per thread per K-tile.
    // chunk c = q*512+tid: row=c>>3 (0..255), slot=c&7, src granule=(c&7)^(row&7)
    const ushort* gA[4];
    const ushort* gB[4];
    int dOf[4];
#pragma unroll
    for (int q = 0; q < 4; q++) {
        const int c = q * 512 + tid;
        const int row = c >> 3;
        const int gsrc = (c & 7) ^ (row & 7);
        gA[q] = Ab + (size_t)min(row, maxrow) * EMB + gsrc * 8;
        gB[q] = Bb + (size_t)row * EMB + gsrc * 8;
        dOf[q] = c * 8;
    }

    // read-side base offsets (ushort units); frag mi at +mi*1024, ni at +ni*1024
    const int swz0 = (lh ^ (l15 & 7)) * 8;         // ks=0: octet lh
    const int swz1 = ((4 + lh) ^ (l15 & 7)) * 8;   // ks=1: octet 4+lh
    const int aRow = (wr * 128 + l15) * 64;
    const int bRow = (wc * 64 + l15) * 64;

    f32x4 acc[8][4] = {};

#define SA(bp_, q_, ko_) gload16(gA[q_] + (ko_), &LDS[(bp_) * 32768] + dOf[q_])
#define SB(bp_, q_, ko_) gload16(gB[q_] + (ko_), &LDS[(bp_) * 32768 + 16384] + dOf[q_])

    // prologue: full stage of tile 0 into buf 0
    SA(0, 0, 0); SA(0, 1, 0); SA(0, 2, 0); SA(0, 3, 0);
    SB(0, 0, 0); SB(0, 1, 0); SB(0, 2, 0); SB(0, 3, 0);
    asm volatile("s_waitcnt vmcnt(0)" ::: "memory");
    __builtin_amdgcn_s_barrier();

#define MF16(I0, I1, I2, I3, A0, A1, A2, A3)                                          \
    acc[I0][0] = __builtin_amdgcn_mfma_f32_16x16x32_bf16(A0, b0, acc[I0][0], 0,0,0);  \
    acc[I0][1] = __builtin_amdgcn_mfma_f32_16x16x32_bf16(A0, b1, acc[I0][1], 0,0,0);  \
    acc[I0][2] = __builtin_amdgcn_mfma_f32_16x16x32_bf16(A0, b2, acc[I0][2], 0,0,0);  \
    acc[I0][3] = __builtin_amdgcn_mfma_f32_16x16x32_bf16(A0, b3, acc[I0][3], 0,0,0);  \
    acc[I1][0] = __builtin_amdgcn_mfma_f32_16x16x32_bf16(A1, b0, acc[I1][0], 0,0,0);  \
    acc[I1][1] = __builtin_amdgcn_mfma_f32_16x16x32_bf16(A1, b1, acc[I1][1], 0,0,0);  \
    acc[I1][2] = __builtin_amdgcn_mfma_f32_16x16x32_bf16(A1, b2, acc[I1][2], 0,0,0);  \
    acc[I1][3] = __builtin_amdgcn_mfma_f32_16x16x32_bf16(A1, b3, acc[I1][3], 0,0,0);  \
    acc[I2][0] = __builtin_amdgcn_mfma_f32_16x16x32_bf16(A2, b0, acc[I2][0], 0,0,0);  \
    acc[I2][1] = __builtin_amdgcn_mfma_f32_16x16x32_bf16(A2, b1, acc[I2][1], 0,0,0);  \
    acc[I2][2] = __builtin_amdgcn_mfma_f32_16x16x32_bf16(A2, b2, acc[I2][2], 0,0,0);  \
    acc[I2][3] = __builtin_amdgcn_mfma_f32_16x16x32_bf16(A2, b3, acc[I2][3], 0,0,0);  \
    acc[I3][0] = __builtin_amdgcn_mfma_f32_16x16x32_bf16(A3, b0, acc[I3][0], 0,0,0);  \
    acc[I3][1] = __builtin_amdgcn_mfma_f32_16x16x32_bf16(A3, b1, acc[I3][1], 0,0,0);  \
    acc[I3][2] = __builtin_amdgcn_mfma_f32_16x16x32_bf16(A3, b2, acc[I3][2], 0,0,0);  \
    acc[I3][3] = __builtin_amdgcn_mfma_f32_16x16x32_bf16(A3, b3, acc[I3][3], 0,0,0);

#pragma unroll 1
    for (int t = 0; t < KT; ++t) {
        const int bp = (t & 1);
        const int po = bp ^ 1;                 // prefetch buffer
        const ushort* Ablk = &LDS[bp * 32768];
        const ushort* Bblk = Ablk + 16384;
        const bool pf = (t + 1 < KT);
        const int ko = (t + 1) * 64;
        short8 b0, b1, b2, b3;

        // ---- phase 0: ks0, mi 0-3 ----
        {
            short8 a0 = *(const short8*)&Ablk[aRow + swz0];
            short8 a1 = *(const short8*)&Ablk[aRow + 1024 + swz0];
            short8 a2 = *(const short8*)&Ablk[aRow + 2048 + swz0];
            short8 a3 = *(const short8*)&Ablk[aRow + 3072 + swz0];
            b0 = *(const short8*)&Bblk[bRow + swz0];
            b1 = *(const short8*)&Bblk[bRow + 1024 + swz0];
            b2 = *(const short8*)&Bblk[bRow + 2048 + swz0];
            b3 = *(const short8*)&Bblk[bRow + 3072 + swz0];
            if (pf) { SA(po, 0, ko); SA(po, 1, ko); SB(po, 0, ko); SB(po, 1, ko); }
            __builtin_amdgcn_s_barrier();
            asm volatile("s_waitcnt lgkmcnt(0)" ::: "memory");
            __builtin_amdgcn_sched_barrier(0);
            __builtin_amdgcn_s_setprio(1);
            MF16(0, 1, 2, 3, a0, a1, a2, a3)
            __builtin_amdgcn_s_setprio(0);
            __builtin_amdgcn_s_barrier();
        }
        // ---- phase 1: ks0, mi 4-7 (b reused) ----
        {
            short8 a4 = *(const short8*)&Ablk[aRow + 4096 + swz0];
            short8 a5 = *(const short8*)&Ablk[aRow + 5120 + swz0];
            short8 a6 = *(const short8*)&Ablk[aRow + 6144 + swz0];
            short8 a7 = *(const short8*)&Ablk[aRow + 7168 + swz0];
            if (pf) { SA(po, 2, ko); SA(po, 3, ko); SB(po, 2, ko); SB(po, 3, ko); }
            __builtin_amdgcn_s_barrier();
            asm volatile("s_waitcnt lgkmcnt(0)" ::: "memory");
            __builtin_amdgcn_sched_barrier(0);
            __builtin_amdgcn_s_setprio(1);
            MF16(4, 5, 6, 7, a4, a5, a6, a7)
            __builtin_amdgcn_s_setprio(0);
            __builtin_amdgcn_s_barrier();
        }
        // ---- phase 2: ks1, mi 0-3 ----
        {
            short8 a0 = *(const short8*)&Ablk[aRow + swz1];
            short8 a1 = *(const short8*)&Ablk[aRow + 1024 + swz1];
            short8 a2 = *(const short8*)&Ablk[aRow + 2048 + swz1];
            short8 a3 = *(const short8*)&Ablk[aRow + 3072 + swz1];
            b0 = *(const short8*)&Bblk[bRow + swz1];
            b1 = *(const short8*)&Bblk[bRow + 1024 + swz1];
            b2 = *(const short8*)&Bblk[bRow + 2048 + swz1];
            b3 = *(const short8*)&Bblk[bRow + 3072 + swz1];
            __builtin_amdgcn_s_barrier();
            asm volatile("s_waitcnt lgkmcnt(0)" ::: "memory");
            __builtin_amdgcn_sched_barrier(0);
            __builtin_amdgcn_s_setprio(1);
            MF16(0, 1, 2, 3, a0, a1, a2, a3)
            __builtin_amdgcn_s_setprio(0);
            __builtin_amdgcn_s_barrier();
        }
        // ---- phase 3: ks1, mi 4-7 ----
        {
            short8 a4 = *(const short8*)&Ablk[aRow + 4096 + swz1];
            short8 a5 = *(const short8*)&Ablk[aRow + 5120 + swz1];
            short8 a6 = *(const short8*)&Ablk[aRow + 6144 + swz1];
            short8 a7 = *(const short8*)&Ablk[aRow + 7168 + swz1];
            __builtin_amdgcn_s_barrier();
            asm volatile("s_waitcnt lgkmcnt(0)" ::: "memory");
            __builtin_amdgcn_sched_barrier(0);
            __builtin_amdgcn_s_setprio(1);
            MF16(4, 5, 6, 7, a4, a5, a6, a7)
            __builtin_amdgcn_s_setprio(0);
            if (pf) asm volatile("s_waitcnt vmcnt(0)" ::: "memory");
            __builtin_amdgcn_s_barrier();
        }
    }
#undef MF16
#undef SA
#undef SB

    // epilogue: bias + activation + bf16 stores (masked rows for o-blocks)
#pragma unroll
    for (int mi = 0; mi < 8; mi++) {
#pragma unroll
        for (int ni = 0; ni < 4; ni++) {
            const int nb = wc * 64 + ni * 16 + l15;
            const float bv = bptr[nb];
            const int rl = wr * 128 + mi * 16 + lh * 4;
#pragma unroll
            for (int r = 0; r < 4; r++) {
                if (rl + r < Mvalid) {
                    float y = acc[mi][ni][r] + bv;
                    float a = use_tanh ? fast_tanh(y) : fast_sigmoid(y);
                    dst[(size_t)(rowbase + rl + r) * HID + colbase + nb] = f2b(a);
                }
            }
        }
    }
}

// ---- kernel 3: fo-pool scan over T; h = o_last * c_last ----
__global__ __launch_bounds__(256) void fo_pool(
    const unsigned* __restrict__ z32, const unsigned* __restrict__ fz32,
    const unsigned* __restrict__ o32, float* __restrict__ hbuf)
{
    const int p = blockIdx.x * 256 + threadIdx.x;  // pairs of h
    float c0 = 0.f, c1 = 0.f;
#pragma unroll 8
    for (int t = 0; t < T_LEN; ++t) {
        unsigned zz = z32[(size_t)t * (B_DIM * HID / 2) + p];
        unsigned ff = fz32[(size_t)t * (B_DIM * HID / 2) + p];
        float z0 = b2f((ushort)(zz & 0xffffu)), z1 = b2f((ushort)(zz >> 16));
        float f0 = b2f((ushort)(ff & 0xffffu)), f1 = b2f((ushort)(ff >> 16));
        c0 += f0 * (z0 - c0);
        c1 += f1 * (z1 - c1);
    }
    unsigned oo = o32[p];
    float o0 = b2f((ushort)(oo & 0xffffu)), o1 = b2f((ushort)(oo >> 16));
    hbuf[2 * p]     = o0 * c0;
    hbuf[2 * p + 1] = o1 * c1;
}

// ---- kernel 4: logits = h @ Wout + bout; log_softmax ----
__global__ __launch_bounds__(64) void classify(
    const float* __restrict__ hbuf, const float* __restrict__ Wout,
    const float* __restrict__ bout, float* __restrict__ out)
{
    __shared__ float hs[HID];
    const int b = blockIdx.x, l = threadIdx.x;
#pragma unroll
    for (int j = 0; j < HID; j += 64) hs[j + l] = hbuf[(size_t)b * HID + j + l];
    __syncthreads();
    float acc = -1e30f;
    if (l < NLAB) {
        float s = bout[l];
#pragma unroll 4
        for (int e = 0; e < HID; e++) s += hs[e] * Wout[(size_t)e * NLAB + l];
        acc = s;
    }
    float m = acc;
#pragma unroll
    for (int off = 32; off; off >>= 1) m = fmaxf(m, __shfl_xor(m, off));
    float ex = (l < NLAB) ? expf(acc - m) : 0.f;
    float sum = ex;
#pragma unroll
    for (int off = 32; off; off >>= 1) sum += __shfl_xor(sum, off);
    if (l < NLAB) out[(size_t)b * NLAB + l] = acc - m - logf(sum);
}

extern "C" void kernel_launch(void* const* d_in, const int* in_sizes, int n_in,
                              void* d_out, int out_size, void* d_ws, size_t ws_size,
                              hipStream_t stream) {
    const int* sent = (const int*)d_in[0];
    const float* emb = (const float*)d_in[1];
    const float* W = (const float*)d_in[2];
    const float* bias = (const float*)d_in[3];
    const float* Wout = (const float*)d_in[4];
    const float* bout = (const float*)d_in[5];
    float* out = (float*)d_out;

    ushort* xb = (ushort*)d_ws;                      // 32768*1024 bf16
    ushort* Wt = xb + (size_t)M_ROWS * EMB;          // 3072*1024 bf16
    ushort* zb = Wt + (size_t)N3H * EMB;             // 32768*1024 bf16
    ushort* fb = zb + (size_t)M_ROWS * HID;          // 32768*1024 bf16
    ushort* ob = fb + (size_t)M_ROWS * HID;          // 128*1024 bf16
    float* hb = (float*)(ob + (size_t)B_DIM * HID);  // 128*1024 f32

    hipLaunchKernelGGL(prep, dim3(2048 + 3072), dim3(256), 0, stream,
                       sent, emb, W, xb, Wt);
    hipLaunchKernelGGL(gemm256, dim3(1024 + 4), dim3(512), 0, stream,
                       xb, Wt, bias, zb, fb, ob);
    hipLaunchKernelGGL(fo_pool, dim3(B_DIM * HID / 2 / 256), dim3(256), 0, stream,
                       (const unsigned*)zb, (const unsigned*)fb,
                       (const unsigned*)ob, hb);
    hipLaunchKernelGGL(classify, dim3(B_DIM), dim3(64), 0, stream,
                       hb, Wout, bout, out);
}

// Round 11
// 322.747 us; speedup vs baseline: 1.2854x; 1.2854x over previous
//
#include <hip/hip_runtime.h>
#include <hip/hip_bf16.h>

#define T_LEN 256
#define B_DIM 128
#define EMB 1024
#define HID 1024
#define NLAB 50
#define M_ROWS (T_LEN * B_DIM)   // 32768
#define N3H 3072
#define KT 16                    // 1024 / BK=64

typedef __attribute__((ext_vector_type(8))) short short8;
typedef __attribute__((ext_vector_type(4))) float f32x4;

// ---- helpers ----
static __device__ __forceinline__ ushort f2b(float x) {
    unsigned u = __builtin_bit_cast(unsigned, x);
    unsigned lsb = (u >> 16) & 1u;
    u += 0x7fffu + lsb;
    return (ushort)(u >> 16);
}
static __device__ __forceinline__ float b2f(ushort u) {
    unsigned v = ((unsigned)u) << 16;
    return __builtin_bit_cast(float, v);
}
static __device__ __forceinline__ void gload16(const ushort* g, ushort* l) {
    __builtin_amdgcn_global_load_lds(
        (const __attribute__((address_space(1))) unsigned int*)g,
        (__attribute__((address_space(3))) unsigned int*)l,
        16, 0, 0);
}
static __device__ __forceinline__ float fast_sigmoid(float y) {
    return 1.f / (1.f + __expf(-y));
}
static __device__ __forceinline__ float fast_tanh(float y) {
    float e = __expf(2.f * y);
    return (e - 1.f) / (e + 1.f);
}

// ---- kernel 1: gather+convert AND W-transpose, fused into one launch ----
// Blocks 0..2047: x = bf16(emb[sentence]) (16 rows each).
// Blocks 2048..5119: Wt[n][k] = bf16(W[k][n]) (32x32 tile each).
__global__ __launch_bounds__(256) void prep(
    const int* __restrict__ sent, const float* __restrict__ emb,
    const float* __restrict__ W,
    ushort* __restrict__ xb, ushort* __restrict__ Wt)
{
    __shared__ float tile[32][33];
    const int wg = blockIdx.x;
    if (wg < 2048) {
        const int row = wg * 16 + (threadIdx.x >> 4);
        const int seg = threadIdx.x & 15;
        const size_t src = (size_t)sent[row] * EMB;
        const float4* ep = (const float4*)(emb + src);
        ushort4* op = (ushort4*)(xb + (size_t)row * EMB);
#pragma unroll
        for (int j = 0; j < 16; j++) {
            float4 v = ep[seg + j * 16];
            ushort4 o;
            o.x = f2b(v.x); o.y = f2b(v.y); o.z = f2b(v.z); o.w = f2b(v.w);
            op[seg + j * 16] = o;
        }
    } else {
        const int bx = wg - 2048;               // 96 n-tiles x 32 k-tiles
        const int n0 = (bx % 96) * 32, k0 = (bx / 96) * 32;
        const int tx = threadIdx.x & 31, ty = threadIdx.x >> 5;   // 32 x 8
#pragma unroll
        for (int j = 0; j < 32; j += 8)
            tile[ty + j][tx] = W[(size_t)(k0 + ty + j) * N3H + n0 + tx];
        __syncthreads();
#pragma unroll
        for (int j = 0; j < 32; j += 8)
            Wt[(size_t)(n0 + ty + j) * EMB + k0 + tx] = f2b(tile[tx][ty + j]);
    }
}

// ---- kernel 2: m97-structure 128x128 GEMM, BK=64, 4 waves, single-buffer ----
// (R8 configuration, verified: 180us, MfmaUtil 34%, 0 bank conflicts.)
// LDS: row-major [128][64] bf16 per matrix (16 KB each). Rows are 128B = 8
// granules of 16B; granule g of row r stored at slot g^(r&7) (involution).
// Staging: linear LDS dest (chunk c = row*8+slot), global source granule
// (c&7)^(row&7) -> permutation stays within the row's 128B, coalesced.
// Read: lane (l15,lh), k-octet o=ks*4+lh at row R: slot o^(R&7). R&7==l15&7,
// so swizzle term is mi/ni-independent. Conflict-free (0 measured).
// Occupancy ~5 blocks/CU (32KB LDS, 76 VGPR) provides TLP latency hiding.
__global__ __launch_bounds__(256) void gemm128(
    const ushort* __restrict__ A, const ushort* __restrict__ Bt,
    const float* __restrict__ bias,
    ushort* __restrict__ zb, ushort* __restrict__ fb, ushort* __restrict__ ob)
{
    __shared__ ushort LA[128 * 64];   // 16 KB
    __shared__ ushort LB[128 * 64];   // 16 KB

    const int tid = threadIdx.x;
    const int lane = tid & 63;
    const int w = tid >> 6;
    const int wr = w >> 1, wc = w & 1;          // 2x2 wave grid, wave-tile 64x64
    const int l15 = lane & 15, lh = lane >> 4;

    const int wg = blockIdx.x;
    const ushort *Ab, *Bb;
    const float* bptr;
    ushort* dst;
    int rowbase, colbase;
    bool use_tanh;
    if (wg < 4096) {
        // XCD-chunked bijective swizzle (4096 % 8 == 0), nt-fastest:
        // 16 consecutive blocks on one XCD share the same A-panel (L2 reuse).
        const int w2 = (wg & 7) * 512 + (wg >> 3);
        const int mt = w2 >> 4, nt = w2 & 15;
        Ab = A + (size_t)mt * 128 * EMB;
        Bb = Bt + (size_t)nt * 128 * EMB;
        bptr = bias + nt * 128;
        rowbase = mt * 128;
        if (nt < 8) { dst = zb; colbase = nt * 128; use_tanh = true; }
        else        { dst = fb; colbase = (nt - 8) * 128; use_tanh = false; }
    } else {
        // o-gate: last 128 rows x cols 2048 + q*128 (all rows valid)
        const int q = wg - 4096;
        Ab = A + (size_t)(M_ROWS - 128) * EMB;
        Bb = Bt + (size_t)(2048 + q * 128) * EMB;
        bptr = bias + 2048 + q * 128;
        rowbase = 0; colbase = q * 128;
        dst = ob; use_tanh = false;
    }

    // stage-side: 4 chunks per matrix per thread; chunk c = q*256 + tid
    const ushort* gA[4];
    const ushort* gB[4];
    int dOf[4];
#pragma unroll
    for (int q = 0; q < 4; q++) {
        const int c = q * 256 + tid;
        const int row = c >> 3;
        const int gsrc = (c & 7) ^ (row & 7);
        gA[q] = Ab + (size_t)row * EMB + gsrc * 8;
        gB[q] = Bb + (size_t)row * EMB + gsrc * 8;
        dOf[q] = c * 8;
    }

    // read-side base offsets (ushort units); frag mi at +mi*1024
    const int swz0 = (lh ^ (l15 & 7)) * 8;         // ks=0: octet lh
    const int swz1 = ((4 + lh) ^ (l15 & 7)) * 8;   // ks=1: octet 4+lh
    const int aRow = (wr * 64 + l15) * 64;
    const int bRow = (wc * 64 + l15) * 64;

    f32x4 acc[4][4] = {};

    for (int kk = 0; kk < KT; ++kk) {
        const int ko = kk * 64;
        gload16(gA[0] + ko, LA + dOf[0]);
        gload16(gA[1] + ko, LA + dOf[1]);
        gload16(gA[2] + ko, LA + dOf[2]);
        gload16(gA[3] + ko, LA + dOf[3]);
        gload16(gB[0] + ko, LB + dOf[0]);
        gload16(gB[1] + ko, LB + dOf[1]);
        gload16(gB[2] + ko, LB + dOf[2]);
        gload16(gB[3] + ko, LB + dOf[3]);
        __syncthreads();

        // ks = 0
        {
            short8 a0 = *(const short8*)&LA[aRow + swz0];
            short8 a1 = *(const short8*)&LA[aRow + 1024 + swz0];
            short8 a2 = *(const short8*)&LA[aRow + 2048 + swz0];
            short8 a3 = *(const short8*)&LA[aRow + 3072 + swz0];
            short8 b0 = *(const short8*)&LB[bRow + swz0];
            short8 b1 = *(const short8*)&LB[bRow + 1024 + swz0];
            short8 b2 = *(const short8*)&LB[bRow + 2048 + swz0];
            short8 b3 = *(const short8*)&LB[bRow + 3072 + swz0];
#pragma unroll
            for (int mi = 0; mi < 4; mi++) {
                const short8 am = (mi == 0) ? a0 : (mi == 1) ? a1 : (mi == 2) ? a2 : a3;
                acc[mi][0] = __builtin_amdgcn_mfma_f32_16x16x32_bf16(am, b0, acc[mi][0], 0, 0, 0);
                acc[mi][1] = __builtin_amdgcn_mfma_f32_16x16x32_bf16(am, b1, acc[mi][1], 0, 0, 0);
                acc[mi][2] = __builtin_amdgcn_mfma_f32_16x16x32_bf16(am, b2, acc[mi][2], 0, 0, 0);
                acc[mi][3] = __builtin_amdgcn_mfma_f32_16x16x32_bf16(am, b3, acc[mi][3], 0, 0, 0);
            }
        }
        // ks = 1
        {
            short8 a0 = *(const short8*)&LA[aRow + swz1];
            short8 a1 = *(const short8*)&LA[aRow + 1024 + swz1];
            short8 a2 = *(const short8*)&LA[aRow + 2048 + swz1];
            short8 a3 = *(const short8*)&LA[aRow + 3072 + swz1];
            short8 b0 = *(const short8*)&LB[bRow + swz1];
            short8 b1 = *(const short8*)&LB[bRow + 1024 + swz1];
            short8 b2 = *(const short8*)&LB[bRow + 2048 + swz1];
            short8 b3 = *(const short8*)&LB[bRow + 3072 + swz1];
#pragma unroll
            for (int mi = 0; mi < 4; mi++) {
                const short8 am = (mi == 0) ? a0 : (mi == 1) ? a1 : (mi == 2) ? a2 : a3;
                acc[mi][0] = __builtin_amdgcn_mfma_f32_16x16x32_bf16(am, b0, acc[mi][0], 0, 0, 0);
                acc[mi][1] = __builtin_amdgcn_mfma_f32_16x16x32_bf16(am, b1, acc[mi][1], 0, 0, 0);
                acc[mi][2] = __builtin_amdgcn_mfma_f32_16x16x32_bf16(am, b2, acc[mi][2], 0, 0, 0);
                acc[mi][3] = __builtin_amdgcn_mfma_f32_16x16x32_bf16(am, b3, acc[mi][3], 0, 0, 0);
            }
        }
        __syncthreads();
    }

    // epilogue: bias + activation + bf16 stores
#pragma unroll
    for (int mi = 0; mi < 4; mi++) {
#pragma unroll
        for (int ni = 0; ni < 4; ni++) {
            const int nb = wc * 64 + ni * 16 + l15;
            const float bv = bptr[nb];
            const int rl = wr * 64 + mi * 16 + lh * 4;
#pragma unroll
            for (int r = 0; r < 4; r++) {
                float y = acc[mi][ni][r] + bv;
                float a = use_tanh ? fast_tanh(y) : fast_sigmoid(y);
                dst[(size_t)(rowbase + rl + r) * HID + colbase + nb] = f2b(a);
            }
        }
    }
}

// ---- kernel 3: fo-pool scan over T; h = o_last * c_last ----
__global__ __launch_bounds__(256) void fo_pool(
    const unsigned* __restrict__ z32, const unsigned* __restrict__ fz32,
    const unsigned* __restrict__ o32, float* __restrict__ hbuf)
{
    const int p = blockIdx.x * 256 + threadIdx.x;  // pairs of h
    float c0 = 0.f, c1 = 0.f;
#pragma unroll 8
    for (int t = 0; t < T_LEN; ++t) {
        unsigned zz = z32[(size_t)t * (B_DIM * HID / 2) + p];
        unsigned ff = fz32[(size_t)t * (B_DIM * HID / 2) + p];
        float z0 = b2f((ushort)(zz & 0xffffu)), z1 = b2f((ushort)(zz >> 16));
        float f0 = b2f((ushort)(ff & 0xffffu)), f1 = b2f((ushort)(ff >> 16));
        c0 += f0 * (z0 - c0);
        c1 += f1 * (z1 - c1);
    }
    unsigned oo = o32[p];
    float o0 = b2f((ushort)(oo & 0xffffu)), o1 = b2f((ushort)(oo >> 16));
    hbuf[2 * p]     = o0 * c0;
    hbuf[2 * p + 1] = o1 * c1;
}

// ---- kernel 4: logits = h @ Wout + bout; log_softmax ----
__global__ __launch_bounds__(64) void classify(
    const float* __restrict__ hbuf, const float* __restrict__ Wout,
    const float* __restrict__ bout, float* __restrict__ out)
{
    __shared__ float hs[HID];
    const int b = blockIdx.x, l = threadIdx.x;
#pragma unroll
    for (int j = 0; j < HID; j += 64) hs[j + l] = hbuf[(size_t)b * HID + j + l];
    __syncthreads();
    float acc = -1e30f;
    if (l < NLAB) {
        float s = bout[l];
#pragma unroll 4
        for (int e = 0; e < HID; e++) s += hs[e] * Wout[(size_t)e * NLAB + l];
        acc = s;
    }
    float m = acc;
#pragma unroll
    for (int off = 32; off; off >>= 1) m = fmaxf(m, __shfl_xor(m, off));
    float ex = (l < NLAB) ? expf(acc - m) : 0.f;
    float sum = ex;
#pragma unroll
    for (int off = 32; off; off >>= 1) sum += __shfl_xor(sum, off);
    if (l < NLAB) out[(size_t)b * NLAB + l] = acc - m - logf(sum);
}

extern "C" void kernel_launch(void* const* d_in, const int* in_sizes, int n_in,
                              void* d_out, int out_size, void* d_ws, size_t ws_size,
                              hipStream_t stream) {
    const int* sent = (const int*)d_in[0];
    const float* emb = (const float*)d_in[1];
    const float* W = (const float*)d_in[2];
    const float* bias = (const float*)d_in[3];
    const float* Wout = (const float*)d_in[4];
    const float* bout = (const float*)d_in[5];
    float* out = (float*)d_out;

    ushort* xb = (ushort*)d_ws;                      // 32768*1024 bf16
    ushort* Wt = xb + (size_t)M_ROWS * EMB;          // 3072*1024 bf16
    ushort* zb = Wt + (size_t)N3H * EMB;             // 32768*1024 bf16
    ushort* fb = zb + (size_t)M_ROWS * HID;          // 32768*1024 bf16
    ushort* ob = fb + (size_t)M_ROWS * HID;          // 128*1024 bf16
    float* hb = (float*)(ob + (size_t)B_DIM * HID);  // 128*1024 f32

    hipLaunchKernelGGL(prep, dim3(2048 + 3072), dim3(256), 0, stream,
                       sent, emb, W, xb, Wt);
    hipLaunchKernelGGL(gemm128, dim3(4096 + 8), dim3(256), 0, stream,
                       xb, Wt, bias, zb, fb, ob);
    hipLaunchKernelGGL(fo_pool, dim3(B_DIM * HID / 2 / 256), dim3(256), 0, stream,
                       (const unsigned*)zb, (const unsigned*)fb,
                       (const unsigned*)ob, hb);
    hipLaunchKernelGGL(classify, dim3(B_DIM), dim3(64), 0, stream,
                       hb, Wout, bout, out);
}